// Round 1
// baseline (481.053 us; speedup 1.0000x reference)
//
#include <hip/hip_runtime.h>

typedef float  f32x4 __attribute__((ext_vector_type(4)));
typedef short  s16x8 __attribute__((ext_vector_type(8)));

#define GLB_AS(p) ((const __attribute__((address_space(1))) unsigned int*)(p))
#define LDS_AS(p) ((__attribute__((address_space(3))) unsigned int*)(p))

__device__ __forceinline__ void gl_lds16(const void* g, void* l) {
  // async global->LDS, 16B per lane; LDS dest = wave-uniform base + lane*16
  __builtin_amdgcn_global_load_lds(GLB_AS(g), LDS_AS(l), 16, 0, 0);
}

__device__ __forceinline__ unsigned short f2bf(float f) {
  union { float f; unsigned u; } v; v.f = f;
  unsigned r = v.u + 0x7fffu + ((v.u >> 16) & 1u);  // RNE
  return (unsigned short)(r >> 16);
}

// ---------------------------------------------------------------------------
// k_prep: blocks [0,32768): one adj row each -> deg (+self loop), dinv=rsqrt,
//         adj->bf16 with +1.0 folded into the diagonal.
//         blocks [32768,33792): x fp32 -> bf16 (2048 elems each)
//         block 33792: W1 (64x128) -> W1t bf16 (128x64)
//         block 33793: W2 (128x128) -> W2t bf16 (128x128)
// ---------------------------------------------------------------------------
__global__ __launch_bounds__(256) void k_prep(
    const float* __restrict__ adj, const float* __restrict__ x,
    const float* __restrict__ W1, const float* __restrict__ W2,
    unsigned short* __restrict__ adjh, unsigned short* __restrict__ xh,
    unsigned short* __restrict__ w1t, unsigned short* __restrict__ w2t,
    float* __restrict__ dinv)
{
  __shared__ float red[4];
  int bid = blockIdx.x, t = threadIdx.x;
  if (bid < 32768) {
    int row = bid & 2047;
    const float4* src = (const float4*)(adj + (size_t)bid * 2048) + t * 2;
    float4 v0 = src[0], v1 = src[1];
    float vals[8] = {v0.x, v0.y, v0.z, v0.w, v1.x, v1.y, v1.z, v1.w};
    int c0 = t * 8;
    float s = 0.f;
    s16x8 ob;
#pragma unroll
    for (int i = 0; i < 8; ++i) {
      float v = vals[i] + ((c0 + i) == row ? 1.0f : 0.0f);  // A_hat = A + I
      s += v;
      ob[i] = (short)f2bf(v);
    }
    *(s16x8*)(adjh + (size_t)bid * 2048 + c0) = ob;
#pragma unroll
    for (int off = 32; off > 0; off >>= 1) s += __shfl_down(s, off, 64);
    if ((t & 63) == 0) red[t >> 6] = s;
    __syncthreads();
    if (t == 0) dinv[bid] = rsqrtf(red[0] + red[1] + red[2] + red[3]);
  } else if (bid < 32768 + 1024) {
    size_t base = (size_t)(bid - 32768) * 2048 + (size_t)t * 8;
    float4 v0 = *(const float4*)(x + base);
    float4 v1 = *(const float4*)(x + base + 4);
    float vals[8] = {v0.x, v0.y, v0.z, v0.w, v1.x, v1.y, v1.z, v1.w};
    s16x8 ob;
#pragma unroll
    for (int i = 0; i < 8; ++i) ob[i] = (short)f2bf(vals[i]);
    *(s16x8*)(xh + base) = ob;
  } else if (bid == 33792) {
#pragma unroll 4
    for (int i = 0; i < 32; ++i) {
      int idx = t * 32 + i; int h = idx >> 6, k = idx & 63;
      w1t[h * 64 + k] = f2bf(W1[k * 128 + h]);
    }
  } else {
#pragma unroll 4
    for (int i = 0; i < 64; ++i) {
      int idx = t * 64 + i; int h = idx >> 7, k = idx & 127;
      w2t[h * 128 + k] = f2bf(W2[k * 128 + h]);
    }
  }
}

// ---------------------------------------------------------------------------
// k_small<K>: C[node 0..127][h 0..127] = A[128xK] @ Wt[128xK]^T, then
//             Zt[b][h][node] = bf16( C * dinv[node] )   (LDS transpose)
// A: [16][2048][K] bf16 (xh K=64, h1 K=128). Wt: [128][K] bf16 (B^T layout).
// grid = 16 batches * 16 m-tiles = 256 blocks, 256 threads, 4 waves (2x2).
// ---------------------------------------------------------------------------
template<int K>
__global__ __launch_bounds__(256) void k_small(
    const unsigned short* __restrict__ A,
    const unsigned short* __restrict__ Wt,
    const float* __restrict__ dinv,
    unsigned short* __restrict__ Zt)
{
  constexpr int CH = K / 8;                       // 16B chunks per row
  constexpr int CSH = (CH == 8) ? 3 : 4;
  constexpr int LDSB = (2 * 128 * K * 2 > 33280) ? 2 * 128 * K * 2 : 33280;
  __shared__ __align__(16) char lds[LDSB];
  unsigned short* As = (unsigned short*)lds;
  unsigned short* Bs = As + 128 * K;
  unsigned short* tr = (unsigned short*)lds;      // reused after compute

  int t = threadIdx.x;
  int w = t >> 6, lane = t & 63;
  int b = blockIdx.x >> 4, m0 = (blockIdx.x & 15) << 7;
  const unsigned short* Ab = A + ((size_t)b * 2048 + m0) * K;

#pragma unroll
  for (int it = 0; it < CH / 2; ++it) {
    int s = it * 256 + t;
    int row = s >> CSH, c = s & (CH - 1);
    int sc = c ^ (row & 7);                       // involution swizzle
    int dst = (it * 256 + (t & 192)) * 16;        // wave-uniform LDS base
    gl_lds16(Ab + (size_t)row * K + sc * 8, (char*)As + dst);
    gl_lds16(Wt + (size_t)row * K + sc * 8, (char*)Bs + dst);
  }
  __syncthreads();

  int wr = w >> 1, wc = w & 1;
  int g = lane >> 4, r16 = lane & 15;
  f32x4 acc[4][4] = {};
#pragma unroll
  for (int kk = 0; kk < K / 32; ++kk) {
    s16x8 af[4], bfr[4];
#pragma unroll
    for (int m = 0; m < 4; ++m) {
      int row = wr * 64 + m * 16 + r16;
      int sc = (kk * 4 + g) ^ (row & 7);
      af[m] = *(const s16x8*)(As + row * K + sc * 8);
    }
#pragma unroll
    for (int n = 0; n < 4; ++n) {
      int row = wc * 64 + n * 16 + r16;
      int sc = (kk * 4 + g) ^ (row & 7);
      bfr[n] = *(const s16x8*)(Bs + row * K + sc * 8);
    }
#pragma unroll
    for (int m = 0; m < 4; ++m)
#pragma unroll
      for (int n = 0; n < 4; ++n)
        acc[m][n] = __builtin_amdgcn_mfma_f32_16x16x32_bf16(af[m], bfr[n], acc[m][n], 0, 0, 0);
  }
  __syncthreads();                                // all LDS reads done

  // scale by dinv[node], write transposed into padded LDS [128][130]
#pragma unroll
  for (int m = 0; m < 4; ++m) {
#pragma unroll
    for (int rr = 0; rr < 4; ++rr) {
      int rloc = wr * 64 + m * 16 + g * 4 + rr;   // C/D: row=(l>>4)*4+reg
      float dv = dinv[b * 2048 + m0 + rloc];
#pragma unroll
      for (int n = 0; n < 4; ++n) {
        int col = wc * 64 + n * 16 + r16;         // C/D: col=l&15
        tr[rloc * 130 + col] = f2bf(acc[m][n][rr] * dv);
      }
    }
  }
  __syncthreads();

  int h = t >> 1, half = t & 1;
  unsigned short* Zrow = Zt + ((size_t)b * 128 + h) * 2048 + m0 + half * 64;
#pragma unroll
  for (int jj = 0; jj < 8; ++jj) {
    s16x8 pk;
#pragma unroll
    for (int i = 0; i < 8; ++i) pk[i] = (short)tr[(half * 64 + jj * 8 + i) * 130 + h];
    *(s16x8*)(Zrow + jj * 8) = pk;
  }
}

// ---------------------------------------------------------------------------
// k_big: C[m 0..63][h 0..127] = Ah[b][m0+..][2048] @ Zt[b][h][2048]^T
//        out = relu(C * dinv[row] + bias[h]); bf16 (H1) or fp32 (final).
// BM=64 BN=128 BK=64, 256 threads, 4 waves at 32x64, grid = 16*32 = 512.
// ---------------------------------------------------------------------------
template<bool BF16OUT>
__global__ __launch_bounds__(256) void k_big(
    const unsigned short* __restrict__ Ah,
    const unsigned short* __restrict__ Zt,
    const float* __restrict__ dinv,
    const float* __restrict__ bias,
    void* __restrict__ outp)
{
  __shared__ __align__(16) unsigned short As[64 * 64];
  __shared__ __align__(16) unsigned short Bs[128 * 64];
  int t = threadIdx.x;
  int w = t >> 6, lane = t & 63;
  int b = blockIdx.x >> 5, mt = blockIdx.x & 31;
  int m0 = mt << 6;
  const unsigned short* Ab = Ah + (size_t)b * 2048 * 2048 + (size_t)m0 * 2048;
  const unsigned short* Zb = Zt + (size_t)b * 128 * 2048;
  int wr = w >> 1, wc = w & 1;
  int g = lane >> 4, r16 = lane & 15;
  f32x4 acc[2][4] = {};

  for (int kt = 0; kt < 32; ++kt) {
    // stage A tile 64x64 (2 iters) + B tile 128x64 (4 iters), swizzled source
#pragma unroll
    for (int it = 0; it < 2; ++it) {
      int s = it * 256 + t;
      int row = s >> 3, c = s & 7;
      int sc = c ^ (row & 7);
      gl_lds16(Ab + (size_t)row * 2048 + kt * 64 + sc * 8,
               (char*)As + (it * 256 + (t & 192)) * 16);
    }
#pragma unroll
    for (int it = 0; it < 4; ++it) {
      int s = it * 256 + t;
      int row = s >> 3, c = s & 7;
      int sc = c ^ (row & 7);
      gl_lds16(Zb + (size_t)row * 2048 + kt * 64 + sc * 8,
               (char*)Bs + (it * 256 + (t & 192)) * 16);
    }
    __syncthreads();                              // vmcnt drained by compiler
#pragma unroll
    for (int kk = 0; kk < 2; ++kk) {
      s16x8 af[2], bfr[4];
#pragma unroll
      for (int m = 0; m < 2; ++m) {
        int row = wr * 32 + m * 16 + r16;
        int sc = (kk * 4 + g) ^ (row & 7);
        af[m] = *(const s16x8*)(As + row * 64 + sc * 8);
      }
#pragma unroll
      for (int n = 0; n < 4; ++n) {
        int row = wc * 64 + n * 16 + r16;
        int sc = (kk * 4 + g) ^ (row & 7);
        bfr[n] = *(const s16x8*)(Bs + row * 64 + sc * 8);
      }
#pragma unroll
      for (int m = 0; m < 2; ++m)
#pragma unroll
        for (int n = 0; n < 4; ++n)
          acc[m][n] = __builtin_amdgcn_mfma_f32_16x16x32_bf16(af[m], bfr[n], acc[m][n], 0, 0, 0);
    }
    __syncthreads();                              // protect LDS before restage
  }

#pragma unroll
  for (int m = 0; m < 2; ++m) {
#pragma unroll
    for (int rr = 0; rr < 4; ++rr) {
      int grow = m0 + wr * 32 + m * 16 + g * 4 + rr;
      float dv = dinv[b * 2048 + grow];
#pragma unroll
      for (int n = 0; n < 4; ++n) {
        int col = wc * 64 + n * 16 + r16;
        float v = fmaxf(acc[m][n][rr] * dv + bias[col], 0.0f);
        size_t off = ((size_t)b * 2048 + grow) * 128 + col;
        if (BF16OUT) ((unsigned short*)outp)[off] = f2bf(v);
        else         ((float*)outp)[off] = v;
      }
    }
  }
}

// ---------------------------------------------------------------------------
extern "C" void kernel_launch(void* const* d_in, const int* in_sizes, int n_in,
                              void* d_out, int out_size, void* d_ws, size_t ws_size,
                              hipStream_t stream)
{
  (void)in_sizes; (void)n_in; (void)out_size; (void)ws_size;
  const float* x   = (const float*)d_in[0];
  const float* adj = (const float*)d_in[1];
  const float* W1  = (const float*)d_in[2];
  const float* b1  = (const float*)d_in[3];
  const float* W2  = (const float*)d_in[4];
  const float* b2  = (const float*)d_in[5];

  char* ws = (char*)d_ws;
  unsigned short* adjh = (unsigned short*)(ws);                    // 134,217,728 B
  unsigned short* xh   = (unsigned short*)(ws + 134217728);        //   4,194,304 B
  unsigned short* w1t  = (unsigned short*)(ws + 138412032);        //      16,384 B
  unsigned short* w2t  = (unsigned short*)(ws + 138428416);        //      32,768 B
  float*          dinv = (float*)         (ws + 138461184);        //     131,072 B
  unsigned short* z1t  = (unsigned short*)(ws + 138592256);        //   8,388,608 B
  unsigned short* h1   = (unsigned short*)(ws + 146980864);        //   8,388,608 B
  unsigned short* z2t  = (unsigned short*)(ws + 155369472);        //   8,388,608 B (end ~156.2 MB)

  k_prep<<<33794, 256, 0, stream>>>(adj, x, W1, W2, adjh, xh, w1t, w2t, dinv);
  k_small<64><<<256, 256, 0, stream>>>(xh, w1t, dinv, z1t);
  k_big<true><<<512, 256, 0, stream>>>(adjh, z1t, dinv, b1, (void*)h1);
  k_small<128><<<256, 256, 0, stream>>>(h1, w2t, dinv, z2t);
  k_big<false><<<512, 256, 0, stream>>>(adjh, z2t, dinv, b2, d_out);
}